// Round 11
// baseline (198.602 us; speedup 1.0000x reference)
//
#include <hip/hip_runtime.h>

#define B_  128
#define N_  32
#define L_  36
#define DS  512
#define DV  1024
#define H_  512
#define P_  496
#define R_  63488      // B_*P_
#define LSE_BLKS 128   // prepended to gemm_fused dispatch
#define FUSE_BLKS (R_ / 128)   // 496

typedef __attribute__((ext_vector_type(8))) short bf16x8;
typedef __attribute__((ext_vector_type(4))) float f32x4;

__device__ __forceinline__ ushort f2bf(float x){
  unsigned u = __builtin_bit_cast(unsigned, x);
  return (ushort)((u + 0x7FFFu + ((u >> 16) & 1u)) >> 16);
}
__device__ __forceinline__ float bf2f(ushort u){
  unsigned v = ((unsigned)u) << 16;
  return __builtin_bit_cast(float, v);
}

// packed product via v_cvt_pk_bf16_f32 (RNE, 1 instr per 2 elems; no builtin on gfx950)
__device__ __forceinline__ bf16x8 pkmul(bf16x8 a, bf16x8 b){
  union { unsigned u[4]; bf16x8 v; } o;
  #pragma unroll
  for (int e = 0; e < 4; ++e){
    float p0 = bf2f((ushort)a[2*e])   * bf2f((ushort)b[2*e]);
    float p1 = bf2f((ushort)a[2*e+1]) * bf2f((ushort)b[2*e+1]);
    asm("v_cvt_pk_bf16_f32 %0, %1, %2" : "=v"(o.u[e]) : "v"(p0), "v"(p1));
  }
  return o.v;
}

__device__ __forceinline__ void gload16(const void* g, void* l){
  __builtin_amdgcn_global_load_lds((const __attribute__((address_space(1))) unsigned*)g,
                                   (__attribute__((address_space(3))) unsigned*)l, 16, 0, 0);
}

__device__ __forceinline__ float wave_sum(float v){
  #pragma unroll
  for (int m = 32; m >= 1; m >>= 1) v += __shfl_xor(v, m);
  return v;
}
__device__ __forceinline__ float wave_max(float v){
  #pragma unroll
  for (int m = 32; m >= 1; m >>= 1) v = fmaxf(v, __shfl_xor(v, m));
  return v;
}

// ---------- merged prep ----------
#define SPAN_F4 524288        // 4096*512/4
#define IMG_F4  1179648       // 128*36*1024/4
#define CONV_BLKS ((SPAN_F4 + IMG_F4) / 256)   // 6656
#define TR_BLKS   (512 * 5)                    // 2560
__global__ void prep_all(const float* __restrict__ span, const float* __restrict__ img,
                         const float* __restrict__ b3,
                         const float* __restrict__ Wg, const float* __restrict__ W1,
                         const float* __restrict__ W2,
                         const float* __restrict__ sm, const float* __restrict__ im,
                         ushort* __restrict__ spbf, ushort* __restrict__ imgbf,
                         float* __restrict__ text,
                         ushort* __restrict__ WgT, ushort* __restrict__ UVBT,
                         ushort* __restrict__ W1cT, ushort* __restrict__ W2T,
                         float* cnt_s, float* cnt_i, int* iu, int* ju, float* loss){
  __shared__ float tile[32][33];
  const int bid = blockIdx.x, tid = threadIdx.x;
  if (bid < CONV_BLKS){
    int idx = bid * 256 + tid;
    if (idx < R_) text[idx] = b3[0];
    const float* src; ushort* dst; int k;
    if (idx < SPAN_F4){ src = span; dst = spbf; k = idx; }
    else              { src = img;  dst = imgbf; k = idx - SPAN_F4; }
    float4 v = *(const float4*)&src[(size_t)k * 4];
    ushort4 o; o.x = f2bf(v.x); o.y = f2bf(v.y); o.z = f2bf(v.z); o.w = f2bf(v.w);
    *(ushort4*)&dst[(size_t)k * 4] = o;
  } else if (bid < CONV_BLKS + TR_BLKS){
    int b = bid - CONV_BLKS;
    int z = b >> 9, rem = b & 511;
    int bx = rem & 31, by = rem >> 5;
    const float* src; ushort* dst; int Nn;
    if      (z == 0){ src = Wg;            dst = WgT;            Nn = 1024; }
    else if (z == 1){ src = W1;            dst = UVBT;           Nn = 512;  }
    else if (z == 2){ src = W1 + 512*512;  dst = UVBT + 512*512; Nn = 512;  }
    else if (z == 3){ src = W1 + 1024*512; dst = W1cT;           Nn = 512;  }
    else            { src = W2;            dst = W2T;            Nn = 512;  }
    if (bx * 32 >= Nn) return;
    int n0 = bx * 32, k0 = by * 32;
    int x = tid & 31, y = tid >> 5;   // 32 x 8
    #pragma unroll
    for (int i = 0; i < 4; ++i) tile[y + 8*i][x] = src[(k0 + y + 8*i) * Nn + n0 + x];
    __syncthreads();
    if (z >= 3){
      // MFMA-fragment-tiled layout: [n>>4][k>>3][n&15][k&7]
      #pragma unroll
      for (int i = 0; i < 4; ++i){
        int n = n0 + y + 8*i, k = k0 + x;
        dst[(n >> 4)*8192 + (k >> 3)*128 + (n & 15)*8 + (k & 7)] = f2bf(tile[x][y + 8*i]);
      }
    } else {
      #pragma unroll
      for (int i = 0; i < 4; ++i) dst[(n0 + y + 8*i) * 512 + k0 + x] = f2bf(tile[x][y + 8*i]);
    }
  } else {
    int t = (bid - CONV_BLKS - TR_BLKS) * 256 + tid;   // [0,512)
    if (t < P_){
      int i = 0, rem = t, cnt = N_ - 1;
      while (rem >= cnt){ rem -= cnt; ++i; --cnt; }
      iu[t] = i; ju[t] = i + 1 + rem;
    }
    if (t < B_){
      float s = 0.f;
      for (int n = 0; n < N_; ++n) s += sm[t*N_ + n];
      cnt_s[t] = s;
    } else if (t < 2*B_){
      int j = t - B_;
      float s = 0.f;
      for (int l = 0; l < L_; ++l) s += im[j*L_ + l];
      cnt_i[j] = s;
    }
    if (t == 0) loss[0] = 0.f;
  }
}

// =====================================================================
// span2_gemm v2 — 256 blocks (full machine), 128x256 tiles, K=512.
// (unchanged from R10)
// =====================================================================
#define S2_LDSA 8192    // ushorts: A[128][64]
#define S2_BUF  24576   // ushorts: A + B[256][64] = 48 KB

__global__ __launch_bounds__(512, 2) void span2_gemm(const ushort* __restrict__ A,
                                                     const ushort* __restrict__ BT2,
                                                     ushort* __restrict__ SG,
                                                     ushort* __restrict__ UV){
  __shared__ ushort lds[2 * S2_BUF];   // 96 KB
  const int bid0 = blockIdx.x;
  const int bid = ((bid0 & 7) << 5) | (bid0 >> 3);
  const size_t m0 = (size_t)(bid & 31) * 128;
  const int ng = (bid >> 5) * 256;
  const int tid = threadIdx.x, wid = tid >> 6, lane = tid & 63;
  const int wr = wid >> 2, wc = wid & 3;
  const int quad = lane >> 4, fm = lane & 15;
  const int swz = ((fm >> 2) & 3) << 4;

  #define S2_STAGE(kt_, dst_) do {                                          \
    _Pragma("unroll")                                                       \
    for (int i_ = 0; i_ < 6; ++i_){                                         \
      int u_ = i_ * 512 + tid;                                              \
      if (u_ < 1024){                                                       \
        int row_ = u_ >> 3, ch_ = (u_ & 7) << 3;                            \
        gload16(A + (m0 + row_) * 512 + (kt_) * 64                          \
                  + (ch_ ^ (((row_ >> 2) & 3) << 4)),                       \
                (dst_) + row_ * 64 + ch_);                                  \
      } else {                                                              \
        int v_ = u_ - 1024;                                                 \
        int row_ = v_ >> 3, ch_ = (v_ & 7) << 3;                            \
        gload16(BT2 + (size_t)(ng + row_) * 512 + (kt_) * 64                \
                  + (ch_ ^ (((row_ >> 2) & 3) << 4)),                       \
                (dst_) + S2_LDSA + row_ * 64 + ch_);                        \
      }                                                                     \
    }                                                                       \
  } while (0)

  f32x4 acc[4][4] = {};
  S2_STAGE(0, lds);
  S2_STAGE(1, lds + S2_BUF);
  #pragma unroll 1
  for (int kt = 0; kt < 8; ++kt){
    if (kt < 7) asm volatile("s_waitcnt vmcnt(6)" ::: "memory");
    else        asm volatile("s_waitcnt vmcnt(0)" ::: "memory");
    __builtin_amdgcn_s_barrier();
    const ushort* bufA = lds + (kt & 1) * S2_BUF;
    const ushort* bufB = bufA + S2_LDSA;
    bf16x8 af[4][2], bg[4][2];
    #pragma unroll
    for (int m = 0; m < 4; ++m)
      #pragma unroll
      for (int kk = 0; kk < 2; ++kk)
        af[m][kk] = *(const bf16x8*)&bufA[(wr*64 + m*16 + fm) * 64
                                          + ((kk*32 + quad*8) ^ swz)];
    #pragma unroll
    for (int n = 0; n < 4; ++n)
      #pragma unroll
      for (int kk = 0; kk < 2; ++kk)
        bg[n][kk] = *(const bf16x8*)&bufB[(wc*64 + n*16 + fm) * 64
                                          + ((kk*32 + quad*8) ^ swz)];
    asm volatile("s_waitcnt lgkmcnt(0)" ::: "memory");
    __builtin_amdgcn_sched_barrier(0);
    __builtin_amdgcn_s_setprio(1);
    #pragma unroll
    for (int kk = 0; kk < 2; ++kk)
      #pragma unroll
      for (int m = 0; m < 4; ++m)
        #pragma unroll
        for (int n = 0; n < 4; ++n)
          acc[m][n] = __builtin_amdgcn_mfma_f32_16x16x32_bf16(
              af[m][kk], bg[n][kk], acc[m][n], 0, 0, 0);
    __builtin_amdgcn_s_setprio(0);
    __builtin_amdgcn_s_barrier();
    if (kt + 2 < 8) S2_STAGE(kt + 2, lds + (kt & 1) * S2_BUF);
  }
  #undef S2_STAGE

  if (ng < 1024){
    #pragma unroll
    for (int m = 0; m < 4; ++m)
      #pragma unroll
      for (int r = 0; r < 4; ++r){
        size_t row = m0 + wr*64 + m*16 + quad*4 + r;
        #pragma unroll
        for (int n = 0; n < 4; ++n){
          int col = ng + wc*64 + n*16 + fm;
          SG[row * 1024 + col] = f2bf(acc[m][n][r]);
        }
      }
  } else {
    const int ngp = ng - 1024;
    const int pcb = (ngp & 512) + (((((ngp & 511) >> 7) + (wc >> 1)) & 3) << 7)
                  + fm * 8 + (wc & 1) * 4;
    #pragma unroll
    for (int m = 0; m < 4; ++m)
      #pragma unroll
      for (int r = 0; r < 4; ++r){
        size_t row = m0 + wr*64 + m*16 + quad*4 + r;
        uint2 pk;
        asm("v_cvt_pk_bf16_f32 %0, %1, %2" : "=v"(pk.x) : "v"(acc[m][0][r]), "v"(acc[m][1][r]));
        asm("v_cvt_pk_bf16_f32 %0, %1, %2" : "=v"(pk.y) : "v"(acc[m][2][r]), "v"(acc[m][3][r]));
        *(uint2*)(UV + row * 1024 + pcb) = pk;
      }
  }
}

// M[b] = SGbf[b] @ imgbf[b]^T; 512 threads (K split 8-way)
__global__ __launch_bounds__(512) void batched_m_mfma(const ushort* __restrict__ SGbf,
                                                      const ushort* __restrict__ imgbf,
                                                      const float* __restrict__ sm,
                                                      float* __restrict__ Mout,
                                                      float* __restrict__ Msum,
                                                      float* __restrict__ Mtot){
  const int b = blockIdx.x;
  const int tid = threadIdx.x, wid = tid >> 6, lane = tid & 63;
  const int quad = lane >> 4, fm = lane & 15;
  __shared__ float red[8][32][48];   // 48 KB
  __shared__ float shr[8];
  f32x4 acc[2][3] = {};
  const int wk = wid * 128;
  const ushort* Ab = SGbf + (size_t)b * 32 * 1024;
  const ushort* Bb = imgbf + (size_t)b * 36 * 1024;
  #pragma unroll
  for (int ks = 0; ks < 4; ++ks){
    const int k = wk + ks * 32 + quad * 8;
    bf16x8 af[2], bg[3];
    af[0] = *(const bf16x8*)&Ab[(0*16 + fm) * 1024 + k];
    af[1] = *(const bf16x8*)&Ab[(1*16 + fm) * 1024 + k];
    bg[0] = *(const bf16x8*)&Bb[(0*16 + fm) * 1024 + k];
    bg[1] = *(const bf16x8*)&Bb[(1*16 + fm) * 1024 + k];
    bg[2] = *(const bf16x8*)&Bb[(2*16 + fm) * 1024 + k];  // rows 36..47 slack
    #pragma unroll
    for (int i = 0; i < 2; ++i)
      #pragma unroll
      for (int j = 0; j < 3; ++j)
        acc[i][j] = __builtin_amdgcn_mfma_f32_16x16x32_bf16(af[i], bg[j], acc[i][j], 0, 0, 0);
  }
  #pragma unroll
  for (int i = 0; i < 2; ++i)
    #pragma unroll
    for (int j = 0; j < 3; ++j)
      #pragma unroll
      for (int r = 0; r < 4; ++r)
        red[wid][i*16 + quad*4 + r][j*16 + fm] = acc[i][j][r];
  __syncthreads();
  float tot = 0.f;
  #pragma unroll
  for (int q = 0; q < 3; ++q){
    int out = tid + 512 * q;
    if (out < N_*L_){
      int n = out / L_, l = out - n * L_;
      float v = 0.f;
      #pragma unroll
      for (int w = 0; w < 8; ++w) v += red[w][n][l];
      Mout[b * (N_*L_) + out] = v;
      tot += v;
    }
  }
  tot = wave_sum(tot);
  if (lane == 0) shr[wid] = tot;
  __syncthreads();
  if (tid == 0){
    float s = 0.f;
    #pragma unroll
    for (int w = 0; w < 8; ++w) s += shr[w];
    Mtot[b] = s;
  }
  if (tid < L_){
    float s = 0.f;
    for (int n = 0; n < N_; ++n){
      float mv = 0.f;
      #pragma unroll
      for (int w = 0; w < 8; ++w) mv += red[w][n][tid];
      s += mv * sm[b*N_ + n];
    }
    Msum[b*L_ + tid] = s;
  }
}

// ---------- lse_loss body (works for 256/512 threads; higher waves duplicate) ----------
__device__ void lse_loss_body(const float* __restrict__ Msum, const float* __restrict__ im,
                              const float* __restrict__ cnt_s, const float* __restrict__ cnt_i,
                              const float* __restrict__ Mtot, float* __restrict__ out,
                              int i, float* sh /*[>=8]*/){
  const int tid = threadIdx.x;
  const int t = tid & 127;            // higher waves duplicate
  const int w4 = tid >> 6, lane = tid & 63;
  float sr = 0.f, sc = 0.f;
  #pragma unroll 4
  for (int l = 0; l < L_; ++l){
    sr += Msum[i*L_ + l] * im[t*L_ + l];
    sc += Msum[t*L_ + l] * im[i*L_ + l];
  }
  const float dr = cnt_s[i] * cnt_i[t];
  const float vr = (dr != 0.f) ? (sr / dr) : (Mtot[i] * (1.f/(float)(N_*L_)));
  const float dc = cnt_s[t] * cnt_i[i];
  const float vc = (dc != 0.f) ? (sc / dc) : (Mtot[t] * (1.f/(float)(N_*L_)));

  float m = wave_max(vr);
  if (lane == 0) sh[w4] = m;
  __syncthreads();
  const float mr = fmaxf(sh[0], sh[1]);
  __syncthreads();
  float e = wave_sum(expf(vr - mr));
  if (lane == 0) sh[w4] = e;
  __syncthreads();
  const float ser = sh[0] + sh[1];
  __syncthreads();
  float rs = wave_sum(vr);
  if (lane == 0) sh[w4] = rs;
  __syncthreads();
  const float rst = sh[0] + sh[1];
  __syncthreads();
  float mc0 = wave_max(vc);
  if (lane == 0) sh[w4] = mc0;
  __syncthreads();
  const float mc = fmaxf(sh[0], sh[1]);
  __syncthreads();
  float ec = wave_sum(expf(vc - mc));
  if (lane == 0) sh[w4] = ec;
  __syncthreads();
  const float sec = sh[0] + sh[1];
  if (tid == 0){
    float contrib = (mr + logf(ser)) + (mc + logf(sec)) - 2.f * rst / (float)B_;
    atomicAdd(out, contrib);
  }
}

// =====================================================================
// FUSED text path v7 — M=128 tile (B L2 traffic halved again).
//   Per block: 128 rows, 512 threads, 8 waves; wave owns all 128 rows x
//   its 64-col slice (acc[8][4]). B panels read exactly once per block
//   -> total B stream 0.5 GB (was 1 GB at M=64). Panel (Z then h1) =
//   128x512 bf16 = 128 KB LDS, 1 block/CU, 8 waves/CU (2/SIMD, same
//   wave count as before). Barrier-free main loops unchanged.
// =====================================================================
__global__ __launch_bounds__(512, 2) void gemm_fused(
    const ushort* __restrict__ spbf, const ushort* __restrict__ W1cT,
    const ushort* __restrict__ W2T, const ushort* __restrict__ UV,
    const float* __restrict__ b1, const float* __restrict__ b2,
    const float* __restrict__ W3, const float* __restrict__ b3,
    const int* __restrict__ iu, const int* __restrict__ ju,
    float* __restrict__ text,
    const float* __restrict__ Msum, const float* __restrict__ im,
    const float* __restrict__ cnt_s, const float* __restrict__ cnt_i,
    const float* __restrict__ Mtot, float* __restrict__ loss){
  __shared__ ushort panel[65536];      // 128 KB: Z-panel (GEMM1), then h1 (GEMM2)
  __shared__ float  partial[8][128];   //   4 KB

  if (blockIdx.x < LSE_BLKS){
    lse_loss_body(Msum, im, cnt_s, cnt_i, Mtot, loss, blockIdx.x, (float*)partial);
    return;
  }
  const size_t m0 = (size_t)(blockIdx.x - LSE_BLKS) * 128;
  const int tid = threadIdx.x, wid = tid >> 6, lane = tid & 63;
  const int wc = wid;                         // 64-col group (0..7); all waves cover rows 0..127
  const int quad = lane >> 4, fm = lane & 15;
  const int f7 = fm & 7;

  // ---- build Z-panel inline: panel[row][ch^(row&7)] = bf16(first*second) ----
  {
    int row = tid >> 2;            // 0..127
    int c0  = tid & 3;
    int row_g = (int)m0 + row;
    int b = row_g / P_, p = row_g - b * P_;
    const ushort* xr = spbf + (size_t)(b * N_ + iu[p]) * 512;
    const ushort* yr = spbf + (size_t)(b * N_ + ju[p]) * 512;
    ushort* pr = panel + row * 512;
    int r7 = row & 7;
    #pragma unroll
    for (int i = 0; i < 16; ++i){
      int ch = c0 + 4*i;
      bf16x8 x = *(const bf16x8*)&xr[ch*8];
      bf16x8 y = *(const bf16x8*)&yr[ch*8];
      *(bf16x8*)&pr[(ch ^ r7) * 8] = pkmul(x, y);
    }
  }
  // per-thread B bases (fragment-tiled: [n>>4][k>>3][n&15][k&7]); wave covers
  // n-tiles wc*4 .. wc*4+3
  const ushort* pB1 = W1cT + wc * 32768 + quad * 128 + fm * 8;
  const ushort* pB2 = W2T  + wc * 32768 + quad * 128 + fm * 8;

  __syncthreads();                             // Z-panel visible to all waves

  #define LOADB(P, D, kt_) {                                                    \
    _Pragma("unroll")                                                           \
    for (int n_ = 0; n_ < 4; ++n_)                                              \
      D[n_] = *(const bf16x8*)&(P)[n_ * 8192 + (kt_) * 512];                    \
  }
  #define ITER(AC, kt_, CUR, NXT, P) {                                          \
    if ((kt_) < 15) LOADB(P, NXT, (kt_) + 1);                                   \
    int c_ = ((((kt_) * 4 + quad) ^ f7) * 8);                                   \
    bf16x8 a_[8];                                                               \
    _Pragma("unroll")                                                           \
    for (int m_ = 0; m_ < 8; ++m_)                                              \
      a_[m_] = *(const bf16x8*)&panel[(m_*16 + fm) * 512 + c_];                 \
    __builtin_amdgcn_s_setprio(1);                                              \
    _Pragma("unroll")                                                           \
    for (int m_ = 0; m_ < 8; ++m_)                                              \
      _Pragma("unroll")                                                         \
      for (int n_ = 0; n_ < 4; ++n_)                                            \
        AC[m_][n_] = __builtin_amdgcn_mfma_f32_16x16x32_bf16(                   \
            a_[m_], CUR[n_], AC[m_][n_], 0, 0, 0);                              \
    __builtin_amdgcn_s_setprio(0);                                              \
  }

  // ================= GEMM1: Z @ W1cT (no barriers) =================
  f32x4 acc[8][4] = {};
  bf16x8 g0[4], g1[4];
  LOADB(pB1, g0, 0);
  #pragma unroll 1
  for (int it = 0; it < 8; ++it){
    ITER(acc, 2*it,     g0, g1, pB1);
    ITER(acc, 2*it + 1, g1, g0, pB1);
  }
  __syncthreads();            // all waves done reading Z-panel
  LOADB(pB2, g0, 0);          // prefetch GEMM2 B kt=0 (regs, overlaps epilogue1)

  // ---- epilogue1: h1 = relu(acc + U + V + b1) -> panel (swizzled bf16) ----
  // UV permuted: the wave's 4 n-values live at one 8B-contiguous quartet:
  // off = ((wc>>1)&3)*128 + fm*8 + (wc&1)*4  (+512 for V-half)
  {
    float b1v[4];
    #pragma unroll
    for (int n = 0; n < 4; ++n) b1v[n] = b1[wc*64 + n*16 + fm];
    const int uvoff = ((wc >> 1) & 3) * 128 + fm * 8 + (wc & 1) * 4;
    #pragma unroll
    for (int m = 0; m < 8; ++m)
      #pragma unroll
      for (int r = 0; r < 4; ++r){
        int rowL = m*16 + quad*4 + r;
        int row_g = (int)m0 + rowL;
        int b = row_g / P_, p = row_g - b * P_;
        union { uint2 u; ushort s[4]; } uv, vv;
        uv.u = *(const uint2*)(UV + (size_t)(b * N_ + iu[p]) * 1024 + uvoff);
        vv.u = *(const uint2*)(UV + (size_t)(b * N_ + ju[p]) * 1024 + 512 + uvoff);
        ushort* pr = panel + rowL * 512;
        int r7 = rowL & 7;
        #pragma unroll
        for (int n = 0; n < 4; n += 2){
          float h0 = fmaxf(acc[m][n][r]   + bf2f(uv.s[n])   + bf2f(vv.s[n])   + b1v[n],   0.f);
          float h1 = fmaxf(acc[m][n+1][r] + bf2f(uv.s[n+1]) + bf2f(vv.s[n+1]) + b1v[n+1], 0.f);
          unsigned pk;
          asm("v_cvt_pk_bf16_f32 %0, %1, %2" : "=v"(pk) : "v"(h0), "v"(h1));
          int col0 = wc*64 + n*16 + fm;
          int col1 = col0 + 16;
          pr[((((col0 >> 3) ^ r7) << 3) + (col0 & 7))] = (ushort)pk;
          pr[((((col1 >> 3) ^ r7) << 3) + (col1 & 7))] = (ushort)(pk >> 16);
        }
      }
  }
  __syncthreads();            // h1 visible

  // ================= GEMM2: h1 @ W2T (no barriers) =================
  f32x4 acc2[8][4] = {};
  #pragma unroll 1
  for (int it = 0; it < 8; ++it){
    ITER(acc2, 2*it,     g0, g1, pB2);
    ITER(acc2, 2*it + 1, g1, g0, pB2);
  }
  #undef ITER
  #undef LOADB

  // ---- epilogue2: text[row] = sum_col relu(h2)*W3 + b3 ----
  {
    float w3v[4], b2v[4];
    #pragma unroll
    for (int n = 0; n < 4; ++n){
      int col = wc*64 + n*16 + fm;
      w3v[n] = W3[col]; b2v[n] = b2[col];
    }
    #pragma unroll
    for (int m = 0; m < 8; ++m)
      #pragma unroll
      for (int r = 0; r < 4; ++r){
        float s = 0.f;
        #pragma unroll
        for (int n = 0; n < 4; ++n){
          float h = fmaxf(acc2[m][n][r] + b2v[n], 0.f);
          s = fmaf(h, w3v[n], s);
        }
        s += __shfl_xor(s, 1); s += __shfl_xor(s, 2);
        s += __shfl_xor(s, 4); s += __shfl_xor(s, 8);
        if (fm == 0) partial[wc][m*16 + quad*4 + r] = s;
      }
  }
  __syncthreads();
  if (tid < 128){
    float s = b3[0];
    #pragma unroll
    for (int w = 0; w < 8; ++w) s += partial[w][tid];
    text[m0 + tid] = s;
  }
}

extern "C" void kernel_launch(void* const* d_in, const int* in_sizes, int n_in,
                              void* d_out, int out_size, void* d_ws, size_t ws_size,
                              hipStream_t stream) {
  const float* span = (const float*)d_in[0];
  const float* img  = (const float*)d_in[1];
  const float* sm   = (const float*)d_in[2];
  const float* im   = (const float*)d_in[3];
  const float* Wg   = (const float*)d_in[4];
  const float* W1   = (const float*)d_in[5];
  const float* b1   = (const float*)d_in[6];
  const float* W2   = (const float*)d_in[7];
  const float* b2   = (const float*)d_in[8];
  const float* W3   = (const float*)d_in[9];
  const float* b3   = (const float*)d_in[10];

  float* out  = (float*)d_out;
  float* loss = out;
  float* Mout = out + 1;
  float* text = out + 1 + B_*N_*L_;

  ushort* wsu  = (ushort*)d_ws;
  ushort* Zbf  = wsu;                          // R_*512 (unused)
  ushort* h1bf = Zbf + (size_t)R_*512;         // R_*512 (unused)
  ushort* UVbf = h1bf + (size_t)R_*512;        // 4096*1024 (col-permuted)
  ushort* SGbf = UVbf + (size_t)4096*1024;     // 4096*1024
  ushort* spbf = SGbf + (size_t)4096*1024;     // 4096*512
  ushort* imgbf= spbf + 4096*512;              // (128*36+12)*1024
  ushort* BT2  = imgbf + (size_t)(B_*L_ + 12)*1024; // WgT then UVBT
  ushort* WgT  = BT2;
  ushort* UVBT = BT2 + 1024*512;
  ushort* W1cT = UVBT + 1024*512;              // 512*512 (fragment-tiled)
  ushort* W2T  = W1cT + 512*512;               // 512*512 (fragment-tiled)
  float* Msum  = (float*)(W2T + 512*512);      // 4608
  float* Mtot  = Msum + B_*L_;
  float* cnt_s = Mtot + B_;
  float* cnt_i = cnt_s + B_;
  int*   iu    = (int*)(cnt_i + B_);           // 496
  int*   ju    = iu + P_;                      // 496

  prep_all<<<CONV_BLKS + TR_BLKS + 2, 256, 0, stream>>>(
      span, img, b3, Wg, W1, W2, sm, im,
      spbf, imgbf, text, WgT, UVBT, W1cT, W2T, cnt_s, cnt_i, iu, ju, loss);

  // span GEMMs (256 blocks of 128x256) — full machine
  span2_gemm<<<256, 512, 0, stream>>>(spbf, BT2, SGbf, UVbf);

  // M path (512 threads, K split 8-way)
  batched_m_mfma<<<B_, 512, 0, stream>>>(SGbf, imgbf, sm, Mout, Msum, Mtot);

  // fused text path (+ lse_loss prepended); Z built inline from spbf
  gemm_fused<<<LSE_BLKS + FUSE_BLKS, 512, 0, stream>>>(
      spbf, W1cT, W2T, UVbf, b1, b2, W3, b3, iu, ju, text,
      Msum, im, cnt_s, cnt_i, Mtot, loss);
}

// Round 12
// 189.698 us; speedup vs baseline: 1.0469x; 1.0469x over previous
//
#include <hip/hip_runtime.h>

#define B_  128
#define N_  32
#define L_  36
#define DS  512
#define DV  1024
#define H_  512
#define P_  496
#define R_  63488      // B_*P_
#define LSE_BLKS 128   // prepended to gemm_fused dispatch
#define FUSE_BLKS (R_ / 64)   // 992

typedef __attribute__((ext_vector_type(8))) short bf16x8;
typedef __attribute__((ext_vector_type(4))) float f32x4;

__device__ __forceinline__ ushort f2bf(float x){
  unsigned u = __builtin_bit_cast(unsigned, x);
  return (ushort)((u + 0x7FFFu + ((u >> 16) & 1u)) >> 16);
}
__device__ __forceinline__ float bf2f(ushort u){
  unsigned v = ((unsigned)u) << 16;
  return __builtin_bit_cast(float, v);
}

// packed product via v_cvt_pk_bf16_f32 (RNE, 1 instr per 2 elems; no builtin on gfx950)
__device__ __forceinline__ bf16x8 pkmul(bf16x8 a, bf16x8 b){
  union { unsigned u[4]; bf16x8 v; } o;
  #pragma unroll
  for (int e = 0; e < 4; ++e){
    float p0 = bf2f((ushort)a[2*e])   * bf2f((ushort)b[2*e]);
    float p1 = bf2f((ushort)a[2*e+1]) * bf2f((ushort)b[2*e+1]);
    asm("v_cvt_pk_bf16_f32 %0, %1, %2" : "=v"(o.u[e]) : "v"(p0), "v"(p1));
  }
  return o.v;
}

__device__ __forceinline__ void gload16(const void* g, void* l){
  __builtin_amdgcn_global_load_lds((const __attribute__((address_space(1))) unsigned*)g,
                                   (__attribute__((address_space(3))) unsigned*)l, 16, 0, 0);
}

__device__ __forceinline__ float wave_sum(float v){
  #pragma unroll
  for (int m = 32; m >= 1; m >>= 1) v += __shfl_xor(v, m);
  return v;
}
__device__ __forceinline__ float wave_max(float v){
  #pragma unroll
  for (int m = 32; m >= 1; m >>= 1) v = fmaxf(v, __shfl_xor(v, m));
  return v;
}

// ---------- merged prep ----------
#define SPAN_F4 524288        // 4096*512/4
#define IMG_F4  1179648       // 128*36*1024/4
#define CONV_BLKS ((SPAN_F4 + IMG_F4) / 256)   // 6656
#define TR_BLKS   (512 * 5)                    // 2560
__global__ void prep_all(const float* __restrict__ span, const float* __restrict__ img,
                         const float* __restrict__ b3,
                         const float* __restrict__ Wg, const float* __restrict__ W1,
                         const float* __restrict__ W2,
                         const float* __restrict__ sm, const float* __restrict__ im,
                         ushort* __restrict__ spbf, ushort* __restrict__ imgbf,
                         float* __restrict__ text,
                         ushort* __restrict__ WgT, ushort* __restrict__ UVBT,
                         ushort* __restrict__ W1cT, ushort* __restrict__ W2T,
                         float* cnt_s, float* cnt_i, int* iu, int* ju, float* loss){
  __shared__ float tile[32][33];
  const int bid = blockIdx.x, tid = threadIdx.x;
  if (bid < CONV_BLKS){
    int idx = bid * 256 + tid;
    if (idx < R_) text[idx] = b3[0];
    const float* src; ushort* dst; int k;
    if (idx < SPAN_F4){ src = span; dst = spbf; k = idx; }
    else              { src = img;  dst = imgbf; k = idx - SPAN_F4; }
    float4 v = *(const float4*)&src[(size_t)k * 4];
    ushort4 o; o.x = f2bf(v.x); o.y = f2bf(v.y); o.z = f2bf(v.z); o.w = f2bf(v.w);
    *(ushort4*)&dst[(size_t)k * 4] = o;
  } else if (bid < CONV_BLKS + TR_BLKS){
    int b = bid - CONV_BLKS;
    int z = b >> 9, rem = b & 511;
    int bx = rem & 31, by = rem >> 5;
    const float* src; ushort* dst; int Nn;
    if      (z == 0){ src = Wg;            dst = WgT;            Nn = 1024; }
    else if (z == 1){ src = W1;            dst = UVBT;           Nn = 512;  }
    else if (z == 2){ src = W1 + 512*512;  dst = UVBT + 512*512; Nn = 512;  }
    else if (z == 3){ src = W1 + 1024*512; dst = W1cT;           Nn = 512;  }
    else            { src = W2;            dst = W2T;            Nn = 512;  }
    if (bx * 32 >= Nn) return;
    int n0 = bx * 32, k0 = by * 32;
    int x = tid & 31, y = tid >> 5;   // 32 x 8
    #pragma unroll
    for (int i = 0; i < 4; ++i) tile[y + 8*i][x] = src[(k0 + y + 8*i) * Nn + n0 + x];
    __syncthreads();
    if (z >= 3){
      // MFMA-fragment-tiled layout: [n>>4][k>>3][n&15][k&7]
      #pragma unroll
      for (int i = 0; i < 4; ++i){
        int n = n0 + y + 8*i, k = k0 + x;
        dst[(n >> 4)*8192 + (k >> 3)*128 + (n & 15)*8 + (k & 7)] = f2bf(tile[x][y + 8*i]);
      }
    } else {
      #pragma unroll
      for (int i = 0; i < 4; ++i) dst[(n0 + y + 8*i) * 512 + k0 + x] = f2bf(tile[x][y + 8*i]);
    }
  } else {
    int t = (bid - CONV_BLKS - TR_BLKS) * 256 + tid;   // [0,512)
    if (t < P_){
      int i = 0, rem = t, cnt = N_ - 1;
      while (rem >= cnt){ rem -= cnt; ++i; --cnt; }
      iu[t] = i; ju[t] = i + 1 + rem;
    }
    if (t < B_){
      float s = 0.f;
      for (int n = 0; n < N_; ++n) s += sm[t*N_ + n];
      cnt_s[t] = s;
    } else if (t < 2*B_){
      int j = t - B_;
      float s = 0.f;
      for (int l = 0; l < L_; ++l) s += im[j*L_ + l];
      cnt_i[j] = s;
    }
    if (t == 0) loss[0] = 0.f;
  }
}

// =====================================================================
// span2_gemm v3 — BK=32 double-buffer, 48 KB LDS -> 2 blocks/CU.
// 256 blocks (full machine), 128x256 tiles, K=512 in 16 kt-steps.
// Per kt: 3 gload16/thread ((128+256)x32x2B / (512x16B)); ledger:
//   prologue stages kt0,kt1 (6 in flight); per kt wait vmcnt(3)
//   (drain kt, keep kt+1); post-read barrier; stage kt+2 (+3 -> 6).
// Reads: af/bg row-major [row][32], lane rows=fm (stride 64B), chunk
// quad*8 -> 8 lanes per 4-bank group = structural min for b128.
// XCD swizzle: bid=(bid0&7)*32+(bid0>>3): each XCD owns one 256-col
// B panel for all 32 m-tiles.
// =====================================================================
#define S2_LDSA 4096    // ushorts: A[128][32]
#define S2_BUF  12288   // ushorts: A + B[256][32] = 24 KB

__global__ __launch_bounds__(512, 4) void span2_gemm(const ushort* __restrict__ A,
                                                     const ushort* __restrict__ BT2,
                                                     ushort* __restrict__ SG,
                                                     ushort* __restrict__ UV){
  __shared__ ushort lds[2 * S2_BUF];   // 48 KB
  const int bid0 = blockIdx.x;
  const int bid = ((bid0 & 7) << 5) | (bid0 >> 3);
  const size_t m0 = (size_t)(bid & 31) * 128;
  const int ng = (bid >> 5) * 256;
  const int tid = threadIdx.x, wid = tid >> 6, lane = tid & 63;
  const int wr = wid >> 2, wc = wid & 3;
  const int quad = lane >> 4, fm = lane & 15;

  #define S2_STAGE(kt_, dst_) do {                                          \
    _Pragma("unroll")                                                       \
    for (int i_ = 0; i_ < 3; ++i_){                                         \
      int u_ = i_ * 512 + tid;                                              \
      if (u_ < 512){                                                        \
        int row_ = u_ >> 2, ch_ = (u_ & 3) << 3;                            \
        gload16(A + (m0 + row_) * 512 + (kt_) * 32 + ch_,                   \
                (dst_) + row_ * 32 + ch_);                                  \
      } else {                                                              \
        int v_ = u_ - 512;                                                  \
        int row_ = v_ >> 2, ch_ = (v_ & 3) << 3;                            \
        gload16(BT2 + (size_t)(ng + row_) * 512 + (kt_) * 32 + ch_,         \
                (dst_) + S2_LDSA + row_ * 32 + ch_);                        \
      }                                                                     \
    }                                                                       \
  } while (0)

  f32x4 acc[4][4] = {};
  S2_STAGE(0, lds);
  S2_STAGE(1, lds + S2_BUF);
  #pragma unroll 1
  for (int kt = 0; kt < 16; ++kt){
    if (kt < 15) asm volatile("s_waitcnt vmcnt(3)" ::: "memory");
    else         asm volatile("s_waitcnt vmcnt(0)" ::: "memory");
    __builtin_amdgcn_s_barrier();
    const ushort* bufA = lds + (kt & 1) * S2_BUF;
    const ushort* bufB = bufA + S2_LDSA;
    bf16x8 af[4], bg[4];
    #pragma unroll
    for (int m = 0; m < 4; ++m)
      af[m] = *(const bf16x8*)&bufA[(wr*64 + m*16 + fm) * 32 + quad*8];
    #pragma unroll
    for (int n = 0; n < 4; ++n)
      bg[n] = *(const bf16x8*)&bufB[(wc*64 + n*16 + fm) * 32 + quad*8];
    asm volatile("s_waitcnt lgkmcnt(0)" ::: "memory");
    __builtin_amdgcn_sched_barrier(0);
    __builtin_amdgcn_s_setprio(1);
    #pragma unroll
    for (int m = 0; m < 4; ++m)
      #pragma unroll
      for (int n = 0; n < 4; ++n)
        acc[m][n] = __builtin_amdgcn_mfma_f32_16x16x32_bf16(
            af[m], bg[n], acc[m][n], 0, 0, 0);
    __builtin_amdgcn_s_setprio(0);
    __builtin_amdgcn_s_barrier();
    if (kt + 2 < 16) S2_STAGE(kt + 2, lds + (kt & 1) * S2_BUF);
  }
  #undef S2_STAGE

  if (ng < 1024){
    #pragma unroll
    for (int m = 0; m < 4; ++m)
      #pragma unroll
      for (int r = 0; r < 4; ++r){
        size_t row = m0 + wr*64 + m*16 + quad*4 + r;
        #pragma unroll
        for (int n = 0; n < 4; ++n){
          int col = ng + wc*64 + n*16 + fm;
          SG[row * 1024 + col] = f2bf(acc[m][n][r]);
        }
      }
  } else {
    const int ngp = ng - 1024;
    const int pcb = (ngp & 512) + (((((ngp & 511) >> 7) + (wc >> 1)) & 3) << 7)
                  + fm * 8 + (wc & 1) * 4;
    #pragma unroll
    for (int m = 0; m < 4; ++m)
      #pragma unroll
      for (int r = 0; r < 4; ++r){
        size_t row = m0 + wr*64 + m*16 + quad*4 + r;
        uint2 pk;
        asm("v_cvt_pk_bf16_f32 %0, %1, %2" : "=v"(pk.x) : "v"(acc[m][0][r]), "v"(acc[m][1][r]));
        asm("v_cvt_pk_bf16_f32 %0, %1, %2" : "=v"(pk.y) : "v"(acc[m][2][r]), "v"(acc[m][3][r]));
        *(uint2*)(UV + row * 1024 + pcb) = pk;
      }
  }
}

// M[b] = SGbf[b] @ imgbf[b]^T; 512 threads (K split 8-way)
__global__ __launch_bounds__(512) void batched_m_mfma(const ushort* __restrict__ SGbf,
                                                      const ushort* __restrict__ imgbf,
                                                      const float* __restrict__ sm,
                                                      float* __restrict__ Mout,
                                                      float* __restrict__ Msum,
                                                      float* __restrict__ Mtot){
  const int b = blockIdx.x;
  const int tid = threadIdx.x, wid = tid >> 6, lane = tid & 63;
  const int quad = lane >> 4, fm = lane & 15;
  __shared__ float red[8][32][48];   // 48 KB
  __shared__ float shr[8];
  f32x4 acc[2][3] = {};
  const int wk = wid * 128;
  const ushort* Ab = SGbf + (size_t)b * 32 * 1024;
  const ushort* Bb = imgbf + (size_t)b * 36 * 1024;
  #pragma unroll
  for (int ks = 0; ks < 4; ++ks){
    const int k = wk + ks * 32 + quad * 8;
    bf16x8 af[2], bg[3];
    af[0] = *(const bf16x8*)&Ab[(0*16 + fm) * 1024 + k];
    af[1] = *(const bf16x8*)&Ab[(1*16 + fm) * 1024 + k];
    bg[0] = *(const bf16x8*)&Bb[(0*16 + fm) * 1024 + k];
    bg[1] = *(const bf16x8*)&Bb[(1*16 + fm) * 1024 + k];
    bg[2] = *(const bf16x8*)&Bb[(2*16 + fm) * 1024 + k];  // rows 36..47 slack
    #pragma unroll
    for (int i = 0; i < 2; ++i)
      #pragma unroll
      for (int j = 0; j < 3; ++j)
        acc[i][j] = __builtin_amdgcn_mfma_f32_16x16x32_bf16(af[i], bg[j], acc[i][j], 0, 0, 0);
  }
  #pragma unroll
  for (int i = 0; i < 2; ++i)
    #pragma unroll
    for (int j = 0; j < 3; ++j)
      #pragma unroll
      for (int r = 0; r < 4; ++r)
        red[wid][i*16 + quad*4 + r][j*16 + fm] = acc[i][j][r];
  __syncthreads();
  float tot = 0.f;
  #pragma unroll
  for (int q = 0; q < 3; ++q){
    int out = tid + 512 * q;
    if (out < N_*L_){
      int n = out / L_, l = out - n * L_;
      float v = 0.f;
      #pragma unroll
      for (int w = 0; w < 8; ++w) v += red[w][n][l];
      Mout[b * (N_*L_) + out] = v;
      tot += v;
    }
  }
  tot = wave_sum(tot);
  if (lane == 0) shr[wid] = tot;
  __syncthreads();
  if (tid == 0){
    float s = 0.f;
    #pragma unroll
    for (int w = 0; w < 8; ++w) s += shr[w];
    Mtot[b] = s;
  }
  if (tid < L_){
    float s = 0.f;
    for (int n = 0; n < N_; ++n){
      float mv = 0.f;
      #pragma unroll
      for (int w = 0; w < 8; ++w) mv += red[w][n][tid];
      s += mv * sm[b*N_ + n];
    }
    Msum[b*L_ + tid] = s;
  }
}

// ---------- lse_loss body (256 threads; waves 2,3 duplicate waves 0,1) ----------
__device__ void lse_loss_body(const float* __restrict__ Msum, const float* __restrict__ im,
                              const float* __restrict__ cnt_s, const float* __restrict__ cnt_i,
                              const float* __restrict__ Mtot, float* __restrict__ out,
                              int i, float* sh /*[4]*/){
  const int tid = threadIdx.x;
  const int t = tid & 127;            // waves 2,3 duplicate
  const int w4 = tid >> 6, lane = tid & 63;
  float sr = 0.f, sc = 0.f;
  #pragma unroll 4
  for (int l = 0; l < L_; ++l){
    sr += Msum[i*L_ + l] * im[t*L_ + l];
    sc += Msum[t*L_ + l] * im[i*L_ + l];
  }
  const float dr = cnt_s[i] * cnt_i[t];
  const float vr = (dr != 0.f) ? (sr / dr) : (Mtot[i] * (1.f/(float)(N_*L_)));
  const float dc = cnt_s[t] * cnt_i[i];
  const float vc = (dc != 0.f) ? (sc / dc) : (Mtot[t] * (1.f/(float)(N_*L_)));

  float m = wave_max(vr);
  if (lane == 0) sh[w4] = m;
  __syncthreads();
  const float mr = fmaxf(sh[0], sh[1]);
  __syncthreads();
  float e = wave_sum(expf(vr - mr));
  if (lane == 0) sh[w4] = e;
  __syncthreads();
  const float ser = sh[0] + sh[1];
  __syncthreads();
  float rs = wave_sum(vr);
  if (lane == 0) sh[w4] = rs;
  __syncthreads();
  const float rst = sh[0] + sh[1];
  __syncthreads();
  float mc0 = wave_max(vc);
  if (lane == 0) sh[w4] = mc0;
  __syncthreads();
  const float mc = fmaxf(sh[0], sh[1]);
  __syncthreads();
  float ec = wave_sum(expf(vc - mc));
  if (lane == 0) sh[w4] = ec;
  __syncthreads();
  const float sec = sh[0] + sh[1];
  if (tid == 0){
    float contrib = (mr + logf(ser)) + (mc + logf(sec)) - 2.f * rst / (float)B_;
    atomicAdd(out, contrib);
  }
}

// =====================================================================
// FUSED text path v6 (R10-proven M=64 geometry) — inline-Z (cvt_pk) +
// both-sides-contiguous UV.  4 waves, 256 thr, 2 blocks/CU.
// =====================================================================
__global__ __launch_bounds__(256, 2) void gemm_fused(
    const ushort* __restrict__ spbf, const ushort* __restrict__ W1cT,
    const ushort* __restrict__ W2T, const ushort* __restrict__ UV,
    const float* __restrict__ b1, const float* __restrict__ b2,
    const float* __restrict__ W3, const float* __restrict__ b3,
    const int* __restrict__ iu, const int* __restrict__ ju,
    float* __restrict__ text,
    const float* __restrict__ Msum, const float* __restrict__ im,
    const float* __restrict__ cnt_s, const float* __restrict__ cnt_i,
    const float* __restrict__ Mtot, float* __restrict__ loss){
  __shared__ ushort panel[32768];      // 64 KB: Z-panel (GEMM1), then h1 (GEMM2)
  __shared__ float  partial[4][64];    //  1 KB

  if (blockIdx.x < LSE_BLKS){
    lse_loss_body(Msum, im, cnt_s, cnt_i, Mtot, loss, blockIdx.x, (float*)partial);
    return;
  }
  const size_t m0 = (size_t)(blockIdx.x - LSE_BLKS) * 64;
  const int tid = threadIdx.x, wid = tid >> 6, lane = tid & 63;
  const int wc = wid;                         // 128-col group; all waves cover rows 0..63
  const int quad = lane >> 4, fm = lane & 15;
  const int f7 = fm & 7;

  // ---- build Z-panel inline: panel[row][ch^(row&7)] = bf16(first*second) ----
  {
    int row = tid >> 2;            // 0..63
    int c0  = tid & 3;
    int row_g = (int)m0 + row;
    int b = row_g / P_, p = row_g - b * P_;
    const ushort* xr = spbf + (size_t)(b * N_ + iu[p]) * 512;
    const ushort* yr = spbf + (size_t)(b * N_ + ju[p]) * 512;
    ushort* pr = panel + row * 512;
    int r7 = row & 7;
    #pragma unroll
    for (int i = 0; i < 16; ++i){
      int ch = c0 + 4*i;
      bf16x8 x = *(const bf16x8*)&xr[ch*8];
      bf16x8 y = *(const bf16x8*)&yr[ch*8];
      *(bf16x8*)&pr[(ch ^ r7) * 8] = pkmul(x, y);
    }
  }
  // per-thread B bases (fragment-tiled: [n>>4][k>>3][n&15][k&7])
  const ushort* pB1 = W1cT + wc * 65536 + quad * 128 + fm * 8;
  const ushort* pB2 = W2T  + wc * 65536 + quad * 128 + fm * 8;
  const int ar0 = (0*16 + fm) * 512;
  const int ar1 = (1*16 + fm) * 512;
  const int ar2 = (2*16 + fm) * 512;
  const int ar3 = (3*16 + fm) * 512;

  __syncthreads();                             // Z-panel visible to all waves

  #define LOADB(P, D, kt_) {                                                    \
    _Pragma("unroll")                                                           \
    for (int n_ = 0; n_ < 8; ++n_)                                              \
      D[n_] = *(const bf16x8*)&(P)[n_ * 8192 + (kt_) * 512];                    \
  }
  #define ITER(AC, kt_, CUR, NXT, P) {                                          \
    if ((kt_) < 15) LOADB(P, NXT, (kt_) + 1);                                   \
    int c_ = ((((kt_) * 4 + quad) ^ f7) * 8);                                   \
    bf16x8 a0 = *(const bf16x8*)&panel[ar0 + c_];                               \
    bf16x8 a1 = *(const bf16x8*)&panel[ar1 + c_];                               \
    bf16x8 a2 = *(const bf16x8*)&panel[ar2 + c_];                               \
    bf16x8 a3 = *(const bf16x8*)&panel[ar3 + c_];                               \
    __builtin_amdgcn_s_setprio(1);                                              \
    _Pragma("unroll")                                                           \
    for (int n_ = 0; n_ < 8; ++n_){                                             \
      AC[0][n_] = __builtin_amdgcn_mfma_f32_16x16x32_bf16(a0, CUR[n_], AC[0][n_], 0, 0, 0); \
      AC[1][n_] = __builtin_amdgcn_mfma_f32_16x16x32_bf16(a1, CUR[n_], AC[1][n_], 0, 0, 0); \
      AC[2][n_] = __builtin_amdgcn_mfma_f32_16x16x32_bf16(a2, CUR[n_], AC[2][n_], 0, 0, 0); \
      AC[3][n_] = __builtin_amdgcn_mfma_f32_16x16x32_bf16(a3, CUR[n_], AC[3][n_], 0, 0, 0); \
    }                                                                           \
    __builtin_amdgcn_s_setprio(0);                                              \
  }

  // ================= GEMM1: Z @ W1cT (no barriers) =================
  f32x4 acc[4][8] = {};
  bf16x8 g0[8], g1[8];
  LOADB(pB1, g0, 0);
  #pragma unroll 1
  for (int it = 0; it < 8; ++it){
    ITER(acc, 2*it,     g0, g1, pB1);
    ITER(acc, 2*it + 1, g1, g0, pB1);
  }
  __syncthreads();            // all waves done reading Z-panel
  LOADB(pB2, g0, 0);          // prefetch GEMM2 B kt=0 (regs, overlaps epilogue1)

  // ---- epilogue1: h1 = relu(acc + U + V + b1) -> panel (swizzled bf16) ----
  {
    float b1v[8];
    #pragma unroll
    for (int n = 0; n < 8; ++n) b1v[n] = b1[wc*128 + n*16 + fm];
    const int uvoff = wc*128 + fm*8;
    #pragma unroll
    for (int m = 0; m < 4; ++m)
      #pragma unroll
      for (int r = 0; r < 4; ++r){
        int rowL = m*16 + quad*4 + r;
        int row_g = (int)m0 + rowL;
        int b = row_g / P_, p = row_g - b * P_;
        bf16x8 uv8 = *(const bf16x8*)(UV + (size_t)(b * N_ + iu[p]) * 1024 + uvoff);
        bf16x8 vv8 = *(const bf16x8*)(UV + (size_t)(b * N_ + ju[p]) * 1024 + 512 + uvoff);
        ushort* pr = panel + rowL * 512;
        int r7 = rowL & 7;
        #pragma unroll
        for (int n = 0; n < 8; n += 2){
          float h0 = fmaxf(acc[m][n][r]   + bf2f((ushort)uv8[n])   + bf2f((ushort)vv8[n])   + b1v[n],   0.f);
          float h1 = fmaxf(acc[m][n+1][r] + bf2f((ushort)uv8[n+1]) + bf2f((ushort)vv8[n+1]) + b1v[n+1], 0.f);
          unsigned pk;
          asm("v_cvt_pk_bf16_f32 %0, %1, %2" : "=v"(pk) : "v"(h0), "v"(h1));
          int col0 = wc*128 + n*16 + fm;
          int col1 = col0 + 16;
          pr[((((col0 >> 3) ^ r7) << 3) + (col0 & 7))] = (ushort)pk;
          pr[((((col1 >> 3) ^ r7) << 3) + (col1 & 7))] = (ushort)(pk >> 16);
        }
      }
  }
  __syncthreads();            // h1 visible

  // ================= GEMM2: h1 @ W2T (no barriers) =================
  f32x4 acc2[4][8] = {};
  #pragma unroll 1
  for (int it = 0; it < 8; ++it){
    ITER(acc2, 2*it,     g0, g1, pB2);
    ITER(acc2, 2*it + 1, g1, g0, pB2);
  }
  #undef ITER
  #undef LOADB

  // ---- epilogue2: text[row] = sum_col relu(h2)*W3 + b3 ----
  {
    float w3v[8], b2v[8];
    #pragma unroll
    for (int n = 0; n < 8; ++n){
      int col = wc*128 + n*16 + fm;
      w3v[n] = W3[col]; b2v[n] = b2[col];
    }
    #pragma unroll
    for (int m = 0; m < 4; ++m)
      #pragma unroll
      for (int r = 0; r < 4; ++r){
        float s = 0.f;
        #pragma unroll
        for (int n = 0; n < 8; ++n){
          float h = fmaxf(acc2[m][n][r] + b2v[n], 0.f);
          s = fmaf(h, w3v[n], s);
        }
        s += __shfl_xor(s, 1); s += __shfl_xor(s, 2);
        s += __shfl_xor(s, 4); s += __shfl_xor(s, 8);
        if (fm == 0) partial[wc][m*16 + quad*4 + r] = s;
      }
  }
  __syncthreads();
  if (tid < 64)
    text[m0 + tid] = partial[0][tid] + partial[1][tid] + partial[2][tid]
                   + partial[3][tid] + b3[0];
}

extern "C" void kernel_launch(void* const* d_in, const int* in_sizes, int n_in,
                              void* d_out, int out_size, void* d_ws, size_t ws_size,
                              hipStream_t stream) {
  const float* span = (const float*)d_in[0];
  const float* img  = (const float*)d_in[1];
  const float* sm   = (const float*)d_in[2];
  const float* im   = (const float*)d_in[3];
  const float* Wg   = (const float*)d_in[4];
  const float* W1   = (const float*)d_in[5];
  const float* b1   = (const float*)d_in[6];
  const float* W2   = (const float*)d_in[7];
  const float* b2   = (const float*)d_in[8];
  const float* W3   = (const float*)d_in[9];
  const float* b3   = (const float*)d_in[10];

  float* out  = (float*)d_out;
  float* loss = out;
  float* Mout = out + 1;
  float* text = out + 1 + B_*N_*L_;

  ushort* wsu  = (ushort*)d_ws;
  ushort* Zbf  = wsu;                          // R_*512 (unused)
  ushort* h1bf = Zbf + (size_t)R_*512;         // R_*512 (unused)
  ushort* UVbf = h1bf + (size_t)R_*512;        // 4096*1024 (col-permuted)
  ushort* SGbf = UVbf + (size_t)4096*1024;     // 4096*1024
  ushort* spbf = SGbf + (size_t)4096*1024;     // 4096*512
  ushort* imgbf= spbf + 4096*512;              // (128*36+12)*1024
  ushort* BT2  = imgbf + (size_t)(B_*L_ + 12)*1024; // WgT then UVBT
  ushort* WgT  = BT2;
  ushort* UVBT = BT2 + 1024*512;
  ushort* W1cT = UVBT + 1024*512;              // 512*512 (fragment-tiled)
  ushort* W2T  = W1cT + 512*512;               // 512*512 (fragment-tiled)
  float* Msum  = (float*)(W2T + 512*512);      // 4608
  float* Mtot  = Msum + B_*L_;
  float* cnt_s = Mtot + B_;
  float* cnt_i = cnt_s + B_;
  int*   iu    = (int*)(cnt_i + B_);           // 496
  int*   ju    = iu + P_;                      // 496

  prep_all<<<CONV_BLKS + TR_BLKS + 2, 256, 0, stream>>>(
      span, img, b3, Wg, W1, W2, sm, im,
      spbf, imgbf, text, WgT, UVBT, W1cT, W2T, cnt_s, cnt_i, iu, ju, loss);

  // span GEMMs (256 blocks of 128x256, 48 KB LDS -> 2 blocks/CU)
  span2_gemm<<<256, 512, 0, stream>>>(spbf, BT2, SGbf, UVbf);

  // M path (512 threads, K split 8-way)
  batched_m_mfma<<<B_, 512, 0, stream>>>(SGbf, imgbf, sm, Mout, Msum, Mtot);

  // fused text path (+ lse_loss prepended); Z built inline from spbf
  gemm_fused<<<LSE_BLKS + FUSE_BLKS, 256, 0, stream>>>(
      spbf, W1cT, W2T, UVbf, b1, b2, W3, b3, iu, ju, text,
      Msum, im, cnt_s, cnt_i, Mtot, loss);
}